// Round 6
// baseline (155.676 us; speedup 1.0000x reference)
//
#include <hip/hip_runtime.h>

typedef __attribute__((ext_vector_type(8))) _Float16 f16x8;
typedef __attribute__((ext_vector_type(4))) float    f32x4;

constexpr int Bsz = 32768;
constexpr int Hn  = 256;
constexpr int In  = 128;
constexpr long long BH = (long long)Bsz * Hn;

// ---------------------------------------------------------------------------
// prep: all weights -> fp16 in ws (half elements):
//   Gh [0,65536) | Gm [65536,131072) | Wr [131072,196608) | Wi [196608,229376)
// Gm = (Gc - fp16(Gc)) * 4096 (scaled split-correction term)
// ---------------------------------------------------------------------------
__global__ __launch_bounds__(256) void k_prep(
    const float* __restrict__ Wi, const float* __restrict__ Wr,
    const float* __restrict__ Gc, _Float16* __restrict__ ws)
{
    const int idx = blockIdx.x * 256 + threadIdx.x;   // 0..65535
    float g = Gc[idx];
    _Float16 gh = (_Float16)g;
    ws[idx] = gh;
    ws[65536 + idx] = (_Float16)((g - (float)gh) * 4096.0f);
    ws[131072 + idx] = (_Float16)Wr[idx];
    if (idx < Hn * In) ws[196608 + idx] = (_Float16)Wi[idx];
}

// ---------------------------------------------------------------------------
// fragment helpers (verified 16x16x32 layouts: lane&15 = row/col, lane>>4 = kq)
// ---------------------------------------------------------------------------
struct f8 { float4 a, b; };

__device__ __forceinline__ f8 loadA8(const float* __restrict__ A, int ld,
                                     int row, int k) {
    const float* p = A + (size_t)row * ld + k;
    f8 r;
    r.a = *(const float4*)p;
    r.b = *(const float4*)(p + 4);
    return r;
}
__device__ __forceinline__ f16x8 cvt_hi(f8 v) {
    float f[8] = {v.a.x, v.a.y, v.a.z, v.a.w, v.b.x, v.b.y, v.b.z, v.b.w};
    f16x8 r;
    #pragma unroll
    for (int k = 0; k < 8; ++k) r[k] = (_Float16)f[k];
    return r;
}
__device__ __forceinline__ f16x8 cvt_mid(f8 v) {
    float f[8] = {v.a.x, v.a.y, v.a.z, v.a.w, v.b.x, v.b.y, v.b.z, v.b.w};
    f16x8 r;
    #pragma unroll
    for (int k = 0; k < 8; ++k) {
        _Float16 h = (_Float16)f[k];
        r[k] = (_Float16)((f[k] - (float)h) * 4096.0f);
    }
    return r;
}

#define MFMA16(A, B, C) __builtin_amdgcn_mfma_f32_16x16x32_f16(A, B, C, 0, 0, 0)

// ---------------------------------------------------------------------------
// main: 1024 blocks x 256 threads, NO LDS, NO barriers.
// Block = 32 rows; wave handles 64 cols (wc). Per k-step (32):
//   acc_c  += v_hi @ Gh^T
//   acc_cm += v_hi @ Gm^T + v_mid @ Gh^T
//   acc_i  += z @ Wr^T  (+ x @ Wi^T for k<128)
// coupling = acc_c + acc_cm/4096 ; epilogue fuses spike/refrac/i-decay.
// ---------------------------------------------------------------------------
__global__ __launch_bounds__(256, 2) void k_main(
    const float* __restrict__ x, const float* __restrict__ z,
    const float* __restrict__ v, const float* __restrict__ cur,
    const float* __restrict__ rho, const _Float16* __restrict__ ws,
    float* __restrict__ out)
{
    const int tid  = threadIdx.x;
    const int lane = tid & 63;
    const int ln = lane & 15, lg = lane >> 4;
    const int wc = (tid >> 6) * 64;
    const int rowBase = blockIdx.x * 32;

    const _Float16* Gh  = ws;
    const _Float16* Gm  = ws + 65536;
    const _Float16* Wr  = ws + 131072;
    const _Float16* Wi  = ws + 196608;

    f32x4 acc_c[2][4], acc_cm[2][4], acc_i[2][4];
    #pragma unroll
    for (int m = 0; m < 2; ++m)
        #pragma unroll
        for (int c = 0; c < 4; ++c) {
            acc_c[m][c]  = (f32x4){0.f, 0.f, 0.f, 0.f};
            acc_cm[m][c] = (f32x4){0.f, 0.f, 0.f, 0.f};
            acc_i[m][c]  = (f32x4){0.f, 0.f, 0.f, 0.f};
        }

    const int r0 = rowBase + ln;        // m=0 fragment row
    const int r1 = rowBase + 16 + ln;   // m=1 fragment row
    const int kq = lg * 8;              // this lane's k-chunk within the step

    #pragma unroll
    for (int t = 0; t < 8; ++t) {
        const int ks = t * 32;
        // ---- A fragments straight from global (HBM, streamed once) ----
        f8 vr0 = loadA8(v, Hn, r0, ks + kq);
        f8 vr1 = loadA8(v, Hn, r1, ks + kq);
        f8 zr0 = loadA8(z, Hn, r0, ks + kq);
        f8 zr1 = loadA8(z, Hn, r1, ks + kq);
        f16x8 vh0 = cvt_hi(vr0),  vh1 = cvt_hi(vr1);
        f16x8 vm0 = cvt_mid(vr0), vm1 = cvt_mid(vr1);
        f16x8 zh0 = cvt_hi(zr0),  zh1 = cvt_hi(zr1);
        f16x8 xh0, xh1;
        if (t < 4) {
            xh0 = cvt_hi(loadA8(x, In, r0, ks + kq));
            xh1 = cvt_hi(loadA8(x, In, r1, ks + kq));
        }
        // ---- B fragments straight from L2-resident fp16 weights ----
        #pragma unroll
        for (int c = 0; c < 4; ++c) {
            const int col = wc + c * 16 + ln;
            f16x8 bgh = *(const f16x8*)(Gh + (size_t)col * Hn + ks + kq);
            f16x8 bgm = *(const f16x8*)(Gm + (size_t)col * Hn + ks + kq);
            f16x8 bwr = *(const f16x8*)(Wr + (size_t)col * Hn + ks + kq);
            acc_c[0][c]  = MFMA16(vh0, bgh, acc_c[0][c]);
            acc_c[1][c]  = MFMA16(vh1, bgh, acc_c[1][c]);
            acc_cm[0][c] = MFMA16(vh0, bgm, acc_cm[0][c]);
            acc_cm[1][c] = MFMA16(vh1, bgm, acc_cm[1][c]);
            acc_cm[0][c] = MFMA16(vm0, bgh, acc_cm[0][c]);
            acc_cm[1][c] = MFMA16(vm1, bgh, acc_cm[1][c]);
            acc_i[0][c]  = MFMA16(zh0, bwr, acc_i[0][c]);
            acc_i[1][c]  = MFMA16(zh1, bwr, acc_i[1][c]);
            if (t < 4) {
                f16x8 bwi = *(const f16x8*)(Wi + (size_t)col * In + ks + kq);
                acc_i[0][c] = MFMA16(xh0, bwi, acc_i[0][c]);
                acc_i[1][c] = MFMA16(xh1, bwi, acc_i[1][c]);
            }
        }
    }

    // fold split-fp16 correction: coupling = acc_c + acc_cm / 4096
    #pragma unroll
    for (int m = 0; m < 2; ++m)
        #pragma unroll
        for (int c = 0; c < 4; ++c)
            acc_c[m][c] = acc_c[m][c] + acc_cm[m][c] * 2.44140625e-4f;

    // ---- epilogue: D map col = lane&15 (+16c+wc), row = m*16 + lg*4 + r ----
    float* out_z   = out;
    float* out_v   = out + BH;
    float* out_i   = out + 2 * BH;
    float* out_rho = out + 3 * BH;

    #pragma unroll
    for (int m = 0; m < 2; ++m) {
        #pragma unroll
        for (int c = 0; c < 4; ++c) {
            const int col = wc + c * 16 + ln;
            const int rowb = rowBase + m * 16 + lg * 4;
            #pragma unroll
            for (int r = 0; r < 4; ++r) {
                const size_t idx = (size_t)(rowb + r) * Hn + col;
                const float vv = v[idx];
                const float ii = cur[idx];
                const float rh = rho[idx];
                const float coup = acc_c[m][c][r];
                float dv   = 0.1f * ((0.0f - vv) + ii) + coup;
                float vdec = vv + dv;
                float zf   = (vdec - 1.0f) > 0.0f ? 1.0f : 0.0f;
                float vnew = (1.0f - zf) * vdec;              // V_RESET = 0
                float mask = rh > 0.0f ? 1.0f : 0.0f;
                vnew = (1.0f - mask) * vnew + mask * vv;
                zf   = (1.0f - mask) * zf;
                float rhon = (1.0f - zf) * fmaxf(rh - mask, 0.0f) + zf * 5.0f;
                out_z[idx]   = zf;
                out_v[idx]   = vnew;
                out_i[idx]   = 0.8f * ii + acc_i[m][c][r];
                out_rho[idx] = rhon;
            }
        }
    }
}

extern "C" void kernel_launch(void* const* d_in, const int* in_sizes, int n_in,
                              void* d_out, int out_size, void* d_ws, size_t ws_size,
                              hipStream_t stream) {
    const float* x   = (const float*)d_in[0];
    const float* z   = (const float*)d_in[1];
    const float* v   = (const float*)d_in[2];
    const float* cur = (const float*)d_in[3];
    const float* rho = (const float*)d_in[4];
    const float* Wi  = (const float*)d_in[5];
    const float* Wr  = (const float*)d_in[6];
    const float* Gc  = (const float*)d_in[7];
    float* out = (float*)d_out;
    _Float16* ws = (_Float16*)d_ws;   // needs 458752 B

    hipLaunchKernelGGL(k_prep, dim3(256), dim3(256), 0, stream, Wi, Wr, Gc, ws);
    hipLaunchKernelGGL(k_main, dim3(Bsz / 32), dim3(256), 0, stream,
                       x, z, v, cur, rho, ws, out);
}

// Round 7
// 138.438 us; speedup vs baseline: 1.1245x; 1.1245x over previous
//
#include <hip/hip_runtime.h>

typedef __attribute__((ext_vector_type(8))) _Float16 f16x8;
typedef __attribute__((ext_vector_type(4))) _Float16 f16x4;
typedef __attribute__((ext_vector_type(4))) float    f32x4;

constexpr int Bsz = 32768;
constexpr int Hn  = 256;
constexpr int In  = 128;
constexpr long long BH = (long long)Bsz * Hn;

// ---------------------------------------------------------------------------
// prep: weights -> fp16, PRE-SWIZZLED into MFMA-fragment-linear order.
// For a [256][K] weight, tile (cg, t): lane l holds W[cg*16 + (l&15)]
// [t*32 + (l>>4)*8 .. +8]. Stored at ((cg*NT + t)*64 + l)*8 halves.
// ws half-layout: Gh [0,64K) | Gm [64K,128K) | Wr [128K,192K) | Wi [192K,224K)
// ---------------------------------------------------------------------------
__global__ __launch_bounds__(256) void k_prep(
    const float* __restrict__ Wi, const float* __restrict__ Wr,
    const float* __restrict__ Gc, _Float16* __restrict__ ws)
{
    const int idx = blockIdx.x * 256 + threadIdx.x;   // 0..65535
    {   // Gh/Gm/Wr: K=256, NT=8
        const int cg = idx >> 12, rem = idx & 4095;
        const int t = rem >> 9, l = (rem >> 3) & 63, j = idx & 7;
        const int col = cg * 16 + (l & 15);
        const int k   = t * 32 + (l >> 4) * 8 + j;
        float g = Gc[col * Hn + k];
        _Float16 gh = (_Float16)g;
        ws[idx]         = gh;
        ws[65536 + idx] = (_Float16)((g - (float)gh) * 4096.0f);
        ws[131072 + idx] = (_Float16)Wr[col * Hn + k];
    }
    if (idx < 32768) {  // Wi: K=128, NT=4
        const int cg = idx >> 11, rem = idx & 2047;
        const int t = rem >> 9, l = (rem >> 3) & 63, j = idx & 7;
        const int col = cg * 16 + (l & 15);
        const int k   = t * 32 + (l >> 4) * 8 + j;
        ws[196608 + idx] = (_Float16)Wi[col * In + k];
    }
}

// ---------------------------------------------------------------------------
// LDS swizzled byte offsets (XOR spreads rows across 16-B granules)
// ---------------------------------------------------------------------------
__device__ __forceinline__ int swzV(int row, int col4) {   // fp32 [32][256]
    return (row * 1024 + col4 * 4) ^ ((row & 7) << 4);
}
__device__ __forceinline__ int swzZ(int row, int colh) {   // fp16 [32][256]
    return (row * 512 + colh * 2) ^ ((row & 7) << 4);
}
__device__ __forceinline__ int swzX(int row, int colh) {   // fp16 [32][128]
    return (row * 256 + colh * 2) ^ ((row & 7) << 4);
}

__device__ __forceinline__ f16x8 cvt_hi2(float4 a, float4 b) {
    float f[8] = {a.x, a.y, a.z, a.w, b.x, b.y, b.z, b.w};
    f16x8 r;
    #pragma unroll
    for (int k = 0; k < 8; ++k) r[k] = (_Float16)f[k];
    return r;
}
__device__ __forceinline__ f16x8 cvt_mid2(float4 a, float4 b) {
    float f[8] = {a.x, a.y, a.z, a.w, b.x, b.y, b.z, b.w};
    f16x8 r;
    #pragma unroll
    for (int k = 0; k < 8; ++k) {
        _Float16 h = (_Float16)f[k];
        r[k] = (_Float16)((f[k] - (float)h) * 4096.0f);
    }
    return r;
}
__device__ __forceinline__ f16x4 cvt4h(float4 a) {
    f16x4 r;
    r[0] = (_Float16)a.x; r[1] = (_Float16)a.y;
    r[2] = (_Float16)a.z; r[3] = (_Float16)a.w;
    return r;
}

#define MFMA16(A, B, C) __builtin_amdgcn_mfma_f32_16x16x32_f16(A, B, C, 0, 0, 0)

// ---------------------------------------------------------------------------
// main: 1024 blocks x 256 thr. LDS: V fp32 32K | Z fp16 16K | X fp16 8K;
// output staging buffer O (32K) aliases Z+X after compute. 5 barriers total.
// ---------------------------------------------------------------------------
__global__ __launch_bounds__(256, 2) void k_main(
    const float* __restrict__ x, const float* __restrict__ z,
    const float* __restrict__ v, const float* __restrict__ cur,
    const float* __restrict__ rho, const _Float16* __restrict__ ws,
    float* __restrict__ out)
{
    __shared__ char smem[65536];
    char* V = smem;
    char* Z = smem + 32768;
    char* X = smem + 49152;
    char* O = smem + 32768;   // aliases Z+X (used after compute only)

    const int tid  = threadIdx.x;
    const int lane = tid & 63;
    const int ln = lane & 15, lg = lane >> 4;
    const int wv = tid >> 6;
    const int wc = wv * 64;
    const int rowBase = blockIdx.x * 32;

    // ---- stage A operands: fully coalesced global float4 reads ----
    {
        const float4* vsrc = (const float4*)(v + (size_t)rowBase * Hn);
        const float4* zsrc = (const float4*)(z + (size_t)rowBase * Hn);
        const float4* xsrc = (const float4*)(x + (size_t)rowBase * In);
        #pragma unroll
        for (int k = 0; k < 8; ++k) {
            const int f = k * 256 + tid;          // float4 index
            const int row = f >> 6, c4 = (f & 63) * 4;
            *(float4*)(V + swzV(row, c4)) = vsrc[f];
        }
        #pragma unroll
        for (int k = 0; k < 8; ++k) {
            const int f = k * 256 + tid;
            const int row = f >> 6, c4 = (f & 63) * 4;
            *(f16x4*)(Z + swzZ(row, c4)) = cvt4h(zsrc[f]);
        }
        #pragma unroll
        for (int k = 0; k < 4; ++k) {
            const int f = k * 256 + tid;
            const int row = f >> 5, c4 = (f & 31) * 4;
            *(f16x4*)(X + swzX(row, c4)) = cvt4h(xsrc[f]);
        }
    }
    __syncthreads();

    // ---- accumulators ----
    f32x4 acc_c[2][4], acc_cm[2][4], acc_i[2][4];
    #pragma unroll
    for (int m = 0; m < 2; ++m)
        #pragma unroll
        for (int c = 0; c < 4; ++c) {
            acc_c[m][c]  = (f32x4){0.f, 0.f, 0.f, 0.f};
            acc_cm[m][c] = (f32x4){0.f, 0.f, 0.f, 0.f};
            acc_i[m][c]  = (f32x4){0.f, 0.f, 0.f, 0.f};
        }

    const _Float16* Gh  = ws;
    const _Float16* Gm  = ws + 65536;
    const _Float16* Wr  = ws + 131072;
    const _Float16* Wi  = ws + 196608;

    // ---- main loop: 8 k-steps of 32; no barriers ----
    #pragma unroll 2
    for (int t = 0; t < 8; ++t) {
        const int kf = t * 32 + lg * 8;
        // A fragments from LDS
        float4 va00 = *(const float4*)(V + swzV(ln, kf));
        float4 va01 = *(const float4*)(V + swzV(ln, kf + 4));
        float4 va10 = *(const float4*)(V + swzV(ln + 16, kf));
        float4 va11 = *(const float4*)(V + swzV(ln + 16, kf + 4));
        f16x8 vh0 = cvt_hi2(va00, va01),  vh1 = cvt_hi2(va10, va11);
        f16x8 vm0 = cvt_mid2(va00, va01), vm1 = cvt_mid2(va10, va11);
        f16x8 zh0 = *(const f16x8*)(Z + swzZ(ln, kf));
        f16x8 zh1 = *(const f16x8*)(Z + swzZ(ln + 16, kf));
        f16x8 xh0, xh1;
        if (t < 4) {
            xh0 = *(const f16x8*)(X + swzX(ln, kf));
            xh1 = *(const f16x8*)(X + swzX(ln + 16, kf));
        }
        // B fragments: pre-swizzled, coalesced, L2-resident
        #pragma unroll
        for (int c = 0; c < 4; ++c) {
            const int cg = wv * 4 + c;
            f16x8 bgh = *(const f16x8*)(Gh + ((size_t)(cg * 8 + t) * 64 + lane) * 8);
            f16x8 bgm = *(const f16x8*)(Gm + ((size_t)(cg * 8 + t) * 64 + lane) * 8);
            f16x8 bwr = *(const f16x8*)(Wr + ((size_t)(cg * 8 + t) * 64 + lane) * 8);
            acc_c[0][c]  = MFMA16(vh0, bgh, acc_c[0][c]);
            acc_c[1][c]  = MFMA16(vh1, bgh, acc_c[1][c]);
            acc_cm[0][c] = MFMA16(vh0, bgm, acc_cm[0][c]);
            acc_cm[1][c] = MFMA16(vh1, bgm, acc_cm[1][c]);
            acc_cm[0][c] = MFMA16(vm0, bgh, acc_cm[0][c]);
            acc_cm[1][c] = MFMA16(vm1, bgh, acc_cm[1][c]);
            acc_i[0][c]  = MFMA16(zh0, bwr, acc_i[0][c]);
            acc_i[1][c]  = MFMA16(zh1, bwr, acc_i[1][c]);
            if (t < 4) {
                f16x8 bwi = *(const f16x8*)(Wi + ((size_t)(cg * 4 + t) * 64 + lane) * 8);
                acc_i[0][c] = MFMA16(xh0, bwi, acc_i[0][c]);
                acc_i[1][c] = MFMA16(xh1, bwi, acc_i[1][c]);
            }
        }
    }

    // fold split-fp16 correction
    #pragma unroll
    for (int m = 0; m < 2; ++m)
        #pragma unroll
        for (int c = 0; c < 4; ++c)
            acc_c[m][c] = acc_c[m][c] + acc_cm[m][c] * 2.44140625e-4f;

    float* out_z   = out;
    float* out_v   = out + BH;
    float* out_i   = out + 2 * BH;
    float* out_rho = out + 3 * BH;

    const int erow = tid >> 3;            // epilogue linear mapping
    const int ecb  = (tid & 7) * 32;

    // ---- pass 1: coupling -> O; compute z/v/rho with coalesced IO ----
    __syncthreads();                      // Z/X reads done before O overwrite
    #pragma unroll
    for (int m = 0; m < 2; ++m)
        #pragma unroll
        for (int c = 0; c < 4; ++c) {
            const int col = wc + c * 16 + ln;
            #pragma unroll
            for (int r = 0; r < 4; ++r)
                *(float*)(O + swzV(m * 16 + lg * 4 + r, col)) = acc_c[m][c][r];
        }
    __syncthreads();
    float4 iisav[8];
    #pragma unroll
    for (int j = 0; j < 8; ++j) {
        const int c4 = ecb + j * 4;
        const size_t gidx = (size_t)(rowBase + erow) * Hn + c4;
        float4 coup = *(const float4*)(O + swzV(erow, c4));
        float4 vv4  = *(const float4*)(V + swzV(erow, c4));
        float4 ii4  = *(const float4*)(cur + gidx);
        float4 rh4  = *(const float4*)(rho + gidx);
        iisav[j] = ii4;
        float zn[4], vn[4], rn[4];
        float vvv[4] = {vv4.x, vv4.y, vv4.z, vv4.w};
        float iii[4] = {ii4.x, ii4.y, ii4.z, ii4.w};
        float rrr[4] = {rh4.x, rh4.y, rh4.z, rh4.w};
        float cpp[4] = {coup.x, coup.y, coup.z, coup.w};
        #pragma unroll
        for (int q = 0; q < 4; ++q) {
            float dv   = 0.1f * ((0.0f - vvv[q]) + iii[q]) + cpp[q];
            float vdec = vvv[q] + dv;
            float zf   = (vdec - 1.0f) > 0.0f ? 1.0f : 0.0f;
            float vnew = (1.0f - zf) * vdec;              // V_RESET = 0
            float mask = rrr[q] > 0.0f ? 1.0f : 0.0f;
            vnew = (1.0f - mask) * vnew + mask * vvv[q];
            zf   = (1.0f - mask) * zf;
            float rhon = (1.0f - zf) * fmaxf(rrr[q] - mask, 0.0f) + zf * 5.0f;
            zn[q] = zf; vn[q] = vnew; rn[q] = rhon;
        }
        *(float4*)(out_z + gidx)   = make_float4(zn[0], zn[1], zn[2], zn[3]);
        *(float4*)(out_v + gidx)   = make_float4(vn[0], vn[1], vn[2], vn[3]);
        *(float4*)(out_rho + gidx) = make_float4(rn[0], rn[1], rn[2], rn[3]);
    }

    // ---- pass 2: acc_i -> O; store i_new coalesced ----
    __syncthreads();
    #pragma unroll
    for (int m = 0; m < 2; ++m)
        #pragma unroll
        for (int c = 0; c < 4; ++c) {
            const int col = wc + c * 16 + ln;
            #pragma unroll
            for (int r = 0; r < 4; ++r)
                *(float*)(O + swzV(m * 16 + lg * 4 + r, col)) = acc_i[m][c][r];
        }
    __syncthreads();
    #pragma unroll
    for (int j = 0; j < 8; ++j) {
        const int c4 = ecb + j * 4;
        const size_t gidx = (size_t)(rowBase + erow) * Hn + c4;
        float4 ai = *(const float4*)(O + swzV(erow, c4));
        float4 ii4 = iisav[j];
        *(float4*)(out_i + gidx) = make_float4(
            0.8f * ii4.x + ai.x, 0.8f * ii4.y + ai.y,
            0.8f * ii4.z + ai.z, 0.8f * ii4.w + ai.w);
    }
}

extern "C" void kernel_launch(void* const* d_in, const int* in_sizes, int n_in,
                              void* d_out, int out_size, void* d_ws, size_t ws_size,
                              hipStream_t stream) {
    const float* x   = (const float*)d_in[0];
    const float* z   = (const float*)d_in[1];
    const float* v   = (const float*)d_in[2];
    const float* cur = (const float*)d_in[3];
    const float* rho = (const float*)d_in[4];
    const float* Wi  = (const float*)d_in[5];
    const float* Wr  = (const float*)d_in[6];
    const float* Gc  = (const float*)d_in[7];
    float* out = (float*)d_out;
    _Float16* ws = (_Float16*)d_ws;   // needs 458752 B

    hipLaunchKernelGGL(k_prep, dim3(256), dim3(256), 0, stream, Wi, Wr, Gc, ws);
    hipLaunchKernelGGL(k_main, dim3(Bsz / 32), dim3(256), 0, stream,
                       x, z, v, cur, rho, ws, out);
}

// Round 8
// 99.519 us; speedup vs baseline: 1.5643x; 1.3911x over previous
//
#include <hip/hip_runtime.h>

typedef __attribute__((ext_vector_type(8))) _Float16 f16x8;
typedef __attribute__((ext_vector_type(4))) _Float16 f16x4;
typedef __attribute__((ext_vector_type(4))) float    f32x4;

constexpr int Bsz = 32768;
constexpr int Hn  = 256;
constexpr int In  = 128;
constexpr long long BH = (long long)Bsz * Hn;

// ---------------------------------------------------------------------------
// prep: weights -> fp16, PRE-SWIZZLED into MFMA-fragment-linear order.
// Tile (cg, t): lane l holds W[cg*16 + (l&15)][t*32 + (l>>4)*8 ..+8],
// stored at ((cg*NT + t)*64 + l)*8 halves. (unchanged from R7)
// ws half-layout: Gh [0,64K) | Gm [64K,128K) | Wr [128K,192K) | Wi [192K,224K)
// ---------------------------------------------------------------------------
__global__ __launch_bounds__(256) void k_prep(
    const float* __restrict__ Wi, const float* __restrict__ Wr,
    const float* __restrict__ Gc, _Float16* __restrict__ ws)
{
    const int idx = blockIdx.x * 256 + threadIdx.x;   // 0..65535
    {   // Gh/Gm/Wr: K=256, NT=8
        const int cg = idx >> 12, rem = idx & 4095;
        const int t = rem >> 9, l = (rem >> 3) & 63, j = idx & 7;
        const int col = cg * 16 + (l & 15);
        const int k   = t * 32 + (l >> 4) * 8 + j;
        float g = Gc[col * Hn + k];
        _Float16 gh = (_Float16)g;
        ws[idx]         = gh;
        ws[65536 + idx] = (_Float16)((g - (float)gh) * 4096.0f);
        ws[131072 + idx] = (_Float16)Wr[col * Hn + k];
    }
    if (idx < 32768) {  // Wi: K=128, NT=4
        const int cg = idx >> 11, rem = idx & 2047;
        const int t = rem >> 9, l = (rem >> 3) & 63, j = idx & 7;
        const int col = cg * 16 + (l & 15);
        const int k   = t * 32 + (l >> 4) * 8 + j;
        ws[196608 + idx] = (_Float16)Wi[col * In + k];
    }
}

// LDS swizzled byte offsets (XOR spreads rows across 16-B granules)
__device__ __forceinline__ int swzV(int row, int col4) {   // fp32 [16][256]
    return (row * 1024 + col4 * 4) ^ ((row & 7) << 4);
}
__device__ __forceinline__ int swzZ(int row, int colh) {   // fp16 [16][256]
    return (row * 512 + colh * 2) ^ ((row & 7) << 4);
}
__device__ __forceinline__ int swzX(int row, int colh) {   // fp16 [16][128]
    return (row * 256 + colh * 2) ^ ((row & 7) << 4);
}

__device__ __forceinline__ f16x8 cvt_hi2(float4 a, float4 b) {
    float f[8] = {a.x, a.y, a.z, a.w, b.x, b.y, b.z, b.w};
    f16x8 r;
    #pragma unroll
    for (int k = 0; k < 8; ++k) r[k] = (_Float16)f[k];
    return r;
}
__device__ __forceinline__ f16x8 cvt_mid2(float4 a, float4 b) {
    float f[8] = {a.x, a.y, a.z, a.w, b.x, b.y, b.z, b.w};
    f16x8 r;
    #pragma unroll
    for (int k = 0; k < 8; ++k) {
        _Float16 h = (_Float16)f[k];
        r[k] = (_Float16)((f[k] - (float)h) * 4096.0f);
    }
    return r;
}
__device__ __forceinline__ f16x4 cvt4h(float4 a) {
    f16x4 r;
    r[0] = (_Float16)a.x; r[1] = (_Float16)a.y;
    r[2] = (_Float16)a.z; r[3] = (_Float16)a.w;
    return r;
}

#define MFMA16(A, B, C) __builtin_amdgcn_mfma_f32_16x16x32_f16(A, B, C, 0, 0, 0)

// ---------------------------------------------------------------------------
// main: 2048 blocks x 256 thr, BT=16 rows. LDS 32 KB:
//   V fp32 [16][256] (16K) | { zh 8K | xh 4K }  <- O fp32 16K aliases zh/xh
// 4 blocks/CU; math order identical to R7 (bit-identical outputs).
// ---------------------------------------------------------------------------
__global__ __launch_bounds__(256, 4) void k_main(
    const float* __restrict__ x, const float* __restrict__ z,
    const float* __restrict__ v, const float* __restrict__ cur,
    const float* __restrict__ rho, const _Float16* __restrict__ ws,
    float* __restrict__ out)
{
    __shared__ char smem[32768];
    char* V = smem;             // 16 KB fp32, lives whole kernel
    char* Z = smem + 16384;     // 8 KB fp16 (k-loop only)
    char* X = smem + 24576;     // 4 KB fp16 (k-loop only)
    char* O = smem + 16384;     // 16 KB fp32 transpose buffer (epilogue only)

    const int tid  = threadIdx.x;
    const int lane = tid & 63;
    const int ln = lane & 15, lg = lane >> 4;
    const int wv = tid >> 6;
    const int wc = wv * 64;
    const int rowBase = blockIdx.x * 16;

    // ---- stage: fully coalesced 1-KB wave reads ----
    {
        const float4* vsrc = (const float4*)(v + (size_t)rowBase * Hn);
        const float4* zsrc = (const float4*)(z + (size_t)rowBase * Hn);
        const float4* xsrc = (const float4*)(x + (size_t)rowBase * In);
        #pragma unroll
        for (int k = 0; k < 4; ++k) {
            const int f = k * 256 + tid;          // float4 index
            const int row = f >> 6, c4 = (f & 63) * 4;
            *(float4*)(V + swzV(row, c4)) = vsrc[f];
        }
        #pragma unroll
        for (int k = 0; k < 4; ++k) {
            const int f = k * 256 + tid;
            const int row = f >> 6, c4 = (f & 63) * 4;
            *(f16x4*)(Z + swzZ(row, c4)) = cvt4h(zsrc[f]);
        }
        #pragma unroll
        for (int k = 0; k < 2; ++k) {
            const int f = k * 256 + tid;
            const int row = f >> 5, c4 = (f & 31) * 4;
            *(f16x4*)(X + swzX(row, c4)) = cvt4h(xsrc[f]);
        }
    }
    __syncthreads();

    f32x4 acc_c[4], acc_cm[4], acc_i[4];
    #pragma unroll
    for (int c = 0; c < 4; ++c) {
        acc_c[c]  = (f32x4){0.f, 0.f, 0.f, 0.f};
        acc_cm[c] = (f32x4){0.f, 0.f, 0.f, 0.f};
        acc_i[c]  = (f32x4){0.f, 0.f, 0.f, 0.f};
    }

    const _Float16* Gh  = ws;
    const _Float16* Gm  = ws + 65536;
    const _Float16* Wr  = ws + 131072;
    const _Float16* Wi  = ws + 196608;

    // ---- main loop: 8 k-steps of 32; no barriers ----
    #pragma unroll 2
    for (int t = 0; t < 8; ++t) {
        const int kf = t * 32 + lg * 8;
        float4 va0 = *(const float4*)(V + swzV(ln, kf));
        float4 va1 = *(const float4*)(V + swzV(ln, kf + 4));
        f16x8 vh = cvt_hi2(va0, va1);
        f16x8 vm = cvt_mid2(va0, va1);
        f16x8 zh = *(const f16x8*)(Z + swzZ(ln, kf));
        f16x8 xh;
        if (t < 4) xh = *(const f16x8*)(X + swzX(ln, kf));
        #pragma unroll
        for (int c = 0; c < 4; ++c) {
            const int cg = wv * 4 + c;
            f16x8 bgh = *(const f16x8*)(Gh + ((size_t)(cg * 8 + t) * 64 + lane) * 8);
            f16x8 bgm = *(const f16x8*)(Gm + ((size_t)(cg * 8 + t) * 64 + lane) * 8);
            f16x8 bwr = *(const f16x8*)(Wr + ((size_t)(cg * 8 + t) * 64 + lane) * 8);
            acc_c[c]  = MFMA16(vh, bgh, acc_c[c]);
            acc_cm[c] = MFMA16(vh, bgm, acc_cm[c]);
            acc_cm[c] = MFMA16(vm, bgh, acc_cm[c]);
            acc_i[c]  = MFMA16(zh, bwr, acc_i[c]);
            if (t < 4) {
                f16x8 bwi = *(const f16x8*)(Wi + ((size_t)(cg * 4 + t) * 64 + lane) * 8);
                acc_i[c] = MFMA16(xh, bwi, acc_i[c]);
            }
        }
    }

    // fold split-fp16 correction: coupling = acc_c + acc_cm / 4096
    #pragma unroll
    for (int c = 0; c < 4; ++c)
        acc_c[c] = acc_c[c] + acc_cm[c] * 2.44140625e-4f;

    float* out_z   = out;
    float* out_v   = out + BH;
    float* out_i   = out + 2 * BH;
    float* out_rho = out + 3 * BH;

    // ---- pass 1: coupling -> O; z/v/rho with 1-KB contiguous wave IO ----
    __syncthreads();                      // Z/X reads done before O overwrite
    #pragma unroll
    for (int c = 0; c < 4; ++c) {
        const int col = wc + c * 16 + ln;
        #pragma unroll
        for (int r = 0; r < 4; ++r)
            *(float*)(O + swzV(lg * 4 + r, col)) = acc_c[c][r];
    }
    __syncthreads();
    float4 iisav[4];
    #pragma unroll
    for (int j = 0; j < 4; ++j) {
        const int f = j * 256 + tid;
        const int row = f >> 6, c4 = (f & 63) * 4;    // lane-contiguous row
        const size_t gidx = (size_t)(rowBase + row) * Hn + c4;
        float4 coup = *(const float4*)(O + swzV(row, c4));
        float4 vv4  = *(const float4*)(V + swzV(row, c4));
        float4 ii4  = *(const float4*)(cur + gidx);
        float4 rh4  = *(const float4*)(rho + gidx);
        iisav[j] = ii4;
        float zn[4], vn[4], rn[4];
        float vvv[4] = {vv4.x, vv4.y, vv4.z, vv4.w};
        float iii[4] = {ii4.x, ii4.y, ii4.z, ii4.w};
        float rrr[4] = {rh4.x, rh4.y, rh4.z, rh4.w};
        float cpp[4] = {coup.x, coup.y, coup.z, coup.w};
        #pragma unroll
        for (int q = 0; q < 4; ++q) {
            float dv   = 0.1f * ((0.0f - vvv[q]) + iii[q]) + cpp[q];
            float vdec = vvv[q] + dv;
            float zf   = (vdec - 1.0f) > 0.0f ? 1.0f : 0.0f;
            float vnew = (1.0f - zf) * vdec;              // V_RESET = 0
            float mask = rrr[q] > 0.0f ? 1.0f : 0.0f;
            vnew = (1.0f - mask) * vnew + mask * vvv[q];
            zf   = (1.0f - mask) * zf;
            float rhon = (1.0f - zf) * fmaxf(rrr[q] - mask, 0.0f) + zf * 5.0f;
            zn[q] = zf; vn[q] = vnew; rn[q] = rhon;
        }
        *(float4*)(out_z + gidx)   = make_float4(zn[0], zn[1], zn[2], zn[3]);
        *(float4*)(out_v + gidx)   = make_float4(vn[0], vn[1], vn[2], vn[3]);
        *(float4*)(out_rho + gidx) = make_float4(rn[0], rn[1], rn[2], rn[3]);
    }

    // ---- pass 2: acc_i -> O; i_new with contiguous stores ----
    __syncthreads();
    #pragma unroll
    for (int c = 0; c < 4; ++c) {
        const int col = wc + c * 16 + ln;
        #pragma unroll
        for (int r = 0; r < 4; ++r)
            *(float*)(O + swzV(lg * 4 + r, col)) = acc_i[c][r];
    }
    __syncthreads();
    #pragma unroll
    for (int j = 0; j < 4; ++j) {
        const int f = j * 256 + tid;
        const int row = f >> 6, c4 = (f & 63) * 4;
        const size_t gidx = (size_t)(rowBase + row) * Hn + c4;
        float4 ai = *(const float4*)(O + swzV(row, c4));
        float4 ii4 = iisav[j];
        *(float4*)(out_i + gidx) = make_float4(
            0.8f * ii4.x + ai.x, 0.8f * ii4.y + ai.y,
            0.8f * ii4.z + ai.z, 0.8f * ii4.w + ai.w);
    }
}

extern "C" void kernel_launch(void* const* d_in, const int* in_sizes, int n_in,
                              void* d_out, int out_size, void* d_ws, size_t ws_size,
                              hipStream_t stream) {
    const float* x   = (const float*)d_in[0];
    const float* z   = (const float*)d_in[1];
    const float* v   = (const float*)d_in[2];
    const float* cur = (const float*)d_in[3];
    const float* rho = (const float*)d_in[4];
    const float* Wi  = (const float*)d_in[5];
    const float* Wr  = (const float*)d_in[6];
    const float* Gc  = (const float*)d_in[7];
    float* out = (float*)d_out;
    _Float16* ws = (_Float16*)d_ws;   // needs 458752 B

    hipLaunchKernelGGL(k_prep, dim3(256), dim3(256), 0, stream, Wi, Wr, Gc, ws);
    hipLaunchKernelGGL(k_main, dim3(Bsz / 16), dim3(256), 0, stream,
                       x, z, v, cur, rho, ws, out);
}